// Round 1
// baseline (1091.766 us; speedup 1.0000x reference)
//
#include <hip/hip_runtime.h>
#include <math.h>

#define CC 256
#define CQN 32          // query/key channels
#define NPIX 4096
#define BATCH 4

// ---------------------------------------------------------------------------
// Projection kernel: q = (Wq x + bq)*m, k = (Wk x + bk)*m, v = Wv x + bv
// grid: BATCH * (NPIX/64) = 256 blocks, 256 threads
// ws layout: q [B][32][N], k [B][32][N], v [B][256][N]
// ---------------------------------------------------------------------------
__global__ __launch_bounds__(256, 2) void proj_kernel(
    const float* __restrict__ x, const float* __restrict__ mask,
    const float* __restrict__ Wq, const float* __restrict__ bq,
    const float* __restrict__ Wk, const float* __restrict__ bk,
    const float* __restrict__ Wv, const float* __restrict__ bv,
    float* __restrict__ qo, float* __restrict__ ko, float* __restrict__ vo)
{
    __shared__ __align__(16) float xs[CC * 64];   // 64 KB, stride 64 (reads are conflict-free)

    const int t = threadIdx.x;
    const int blk = blockIdx.x;
    const int b = blk >> 6;            // 64 pixel tiles per batch
    const int n0 = (blk & 63) * 64;
    const float* xb = x + (size_t)b * CC * NPIX + n0;

    // stage x tile [256 c][64 p]
    {
        const int p4 = (t & 15) * 4;
        const int c0 = t >> 4;                    // 0..15
        #pragma unroll
        for (int it = 0; it < 16; ++it) {
            int c = c0 + it * 16;
            float4 xv = *(const float4*)(xb + (size_t)c * NPIX + p4);
            *(float4*)(xs + c * 64 + p4) = xv;
        }
    }
    __syncthreads();

    const int p = t & 63;
    const int og = t >> 6;             // wave id, 0..3 (wave-uniform)
    const float mval = mask[(size_t)b * NPIX + n0 + p];

    for (int grp = 0; grp < 10; ++grp) {
        const int o = og * 80 + grp * 8;          // wave-uniform; 8-groups never straddle q/k/v
        const float* Wrow; const float* bias; float* dst; int rows; int oc; bool domask;
        if (o < 32)      { Wrow = Wq; bias = bq; dst = qo; rows = CQN; oc = o;      domask = true;  }
        else if (o < 64) { Wrow = Wk; bias = bk; dst = ko; rows = CQN; oc = o - 32; domask = true;  }
        else             { Wrow = Wv; bias = bv; dst = vo; rows = CC;  oc = o - 64; domask = false; }

        float acc[8];
        #pragma unroll
        for (int i = 0; i < 8; ++i) acc[i] = 0.0f;

        const float* W0 = Wrow + (size_t)oc * CC;
        for (int c = 0; c < CC; c += 4) {
            float xv0 = xs[(c    ) * 64 + p];
            float xv1 = xs[(c + 1) * 64 + p];
            float xv2 = xs[(c + 2) * 64 + p];
            float xv3 = xs[(c + 3) * 64 + p];
            #pragma unroll
            for (int i = 0; i < 8; ++i) {
                float4 wv = *(const float4*)(W0 + i * CC + c);
                acc[i] += wv.x * xv0 + wv.y * xv1 + wv.z * xv2 + wv.w * xv3;
            }
        }
        #pragma unroll
        for (int i = 0; i < 8; ++i) {
            float r = acc[i] + bias[oc + i];
            if (domask) r *= mval;
            dst[((size_t)b * rows + oc + i) * NPIX + n0 + p] = r;
        }
    }
}

// ---------------------------------------------------------------------------
// Flash-style attention: per block = one (batch, 32-query tile).
// Iterates 128 key tiles of 32, online softmax, PV accumulated in registers.
// ---------------------------------------------------------------------------
#define TI 32
#define TJ 32
#define QS 36          // q_lds stride  [c][i]
#define KS 36          // k_lds stride  [c][j]
#define VS 257         // v_lds stride  [j][c]  (transposed: PV reads conflict-free)
#define PS 34          // p_lds stride  [i][j]
#define OTS 33         // out-tile stride [c][i]

__global__ __launch_bounds__(256, 3) void attn_kernel(
    const float* __restrict__ q, const float* __restrict__ k, const float* __restrict__ v,
    const float* __restrict__ x, const float* __restrict__ gamma,
    float* __restrict__ out)
{
    __shared__ __align__(16) float smem[11712];   // 46.8 KB
    float* q_lds = smem;                //  32*36 = 1152
    float* k_lds = smem + 1152;         //  32*36 = 1152
    float* v_lds = smem + 2304;         //  32*257 = 8224
    float* p_lds = smem + 10528;        //  32*34 = 1088
    float* m_s   = smem + 11616;        //  32
    float* l_s   = smem + 11648;        //  32
    float* a_s   = smem + 11680;        //  32

    const int t = threadIdx.x;
    const int b  = blockIdx.x >> 7;               // 128 query tiles per batch
    const int i0 = (blockIdx.x & 127) * TI;

    const float* qb = q + (size_t)b * CQN * NPIX + i0;
    const float* kb = k + (size_t)b * CQN * NPIX;
    const float* vb = v + (size_t)b * CC * NPIX;

    // stage q tile [32 c][32 i]
    {
        const int c = t >> 3;           // 0..31
        const int i4 = (t & 7) * 4;
        float4 qv = *(const float4*)(qb + (size_t)c * NPIX + i4);
        *(float4*)(q_lds + c * QS + i4) = qv;
    }
    if (t < TI) { m_s[t] = -INFINITY; l_s[t] = 0.0f; }

    // phase-1 identity: i = t>>3, 4 j's at j8*4
    const int p1_i  = t >> 3;
    const int p1_j8 = t & 7;
    // phase-2 identity: 4 i rows (ib..ib+3), 8 channels c = cg + 32*ci
    const int ig = t >> 5;
    const int cg = t & 31;
    const int ib = ig * 4;

    float acc[4][8];
    #pragma unroll
    for (int ii = 0; ii < 4; ++ii)
        #pragma unroll
        for (int ci = 0; ci < 8; ++ci) acc[ii][ci] = 0.0f;

    for (int jt = 0; jt < NPIX / TJ; ++jt) {
        const int j0 = jt * TJ;
        __syncthreads();   // previous phase-2 done → safe to overwrite k/v tiles

        // load k tile [32 c][32 j]
        {
            const int c = t >> 3;
            const int j4 = (t & 7) * 4;
            float4 kv = *(const float4*)(kb + (size_t)c * NPIX + j0 + j4);
            *(float4*)(k_lds + c * KS + j4) = kv;
        }
        // load v tile transposed → v_lds[j][c]
        {
            const int j4 = (t & 7) * 4;
            const int c0 = t >> 3;                 // 0..31
            #pragma unroll
            for (int it = 0; it < 8; ++it) {
                int c = c0 + it * 32;
                float4 vv = *(const float4*)(vb + (size_t)c * NPIX + j0 + j4);
                v_lds[(j4 + 0) * VS + c] = vv.x;
                v_lds[(j4 + 1) * VS + c] = vv.y;
                v_lds[(j4 + 2) * VS + c] = vv.z;
                v_lds[(j4 + 3) * VS + c] = vv.w;
            }
        }
        __syncthreads();

        // ---- phase 1: energy + online softmax stats ----
        {
            float e0 = 0, e1 = 0, e2 = 0, e3 = 0;
            #pragma unroll 8
            for (int c = 0; c < CQN; ++c) {
                float qv = q_lds[c * QS + p1_i];
                float4 kv = *(const float4*)(k_lds + c * KS + p1_j8 * 4);
                e0 += qv * kv.x; e1 += qv * kv.y; e2 += qv * kv.z; e3 += qv * kv.w;
            }
            float tmax = fmaxf(fmaxf(e0, e1), fmaxf(e2, e3));
            tmax = fmaxf(tmax, __shfl_xor(tmax, 1));
            tmax = fmaxf(tmax, __shfl_xor(tmax, 2));
            tmax = fmaxf(tmax, __shfl_xor(tmax, 4));
            float m_old = m_s[p1_i];
            float m_new = fmaxf(m_old, tmax);
            e0 = __expf(e0 - m_new); e1 = __expf(e1 - m_new);
            e2 = __expf(e2 - m_new); e3 = __expf(e3 - m_new);
            float ls = e0 + e1 + e2 + e3;
            ls += __shfl_xor(ls, 1);
            ls += __shfl_xor(ls, 2);
            ls += __shfl_xor(ls, 4);
            float a = __expf(m_old - m_new);       // first tile: exp(-inf) = 0
            if (p1_j8 == 0) {
                m_s[p1_i] = m_new;
                l_s[p1_i] = l_s[p1_i] * a + ls;
                a_s[p1_i] = a;
            }
            float2* pp = (float2*)(p_lds + p1_i * PS + p1_j8 * 4);
            pp[0] = make_float2(e0, e1);
            pp[1] = make_float2(e2, e3);
        }
        __syncthreads();

        // ---- phase 2: acc = acc*alpha + P @ V ----
        {
            float a0 = a_s[ib + 0], a1 = a_s[ib + 1], a2 = a_s[ib + 2], a3 = a_s[ib + 3];
            #pragma unroll
            for (int ci = 0; ci < 8; ++ci) {
                acc[0][ci] *= a0; acc[1][ci] *= a1; acc[2][ci] *= a2; acc[3][ci] *= a3;
            }
            for (int j = 0; j < TJ; j += 2) {
                float2 p0 = *(const float2*)(p_lds + (ib + 0) * PS + j);
                float2 p1 = *(const float2*)(p_lds + (ib + 1) * PS + j);
                float2 p2 = *(const float2*)(p_lds + (ib + 2) * PS + j);
                float2 p3 = *(const float2*)(p_lds + (ib + 3) * PS + j);
                const float* va = v_lds + (j    ) * VS + cg;
                const float* vb2 = v_lds + (j + 1) * VS + cg;
                #pragma unroll
                for (int ci = 0; ci < 8; ++ci) {
                    float v0 = va[ci * 32];
                    float v1 = vb2[ci * 32];
                    acc[0][ci] += p0.x * v0 + p0.y * v1;
                    acc[1][ci] += p1.x * v0 + p1.y * v1;
                    acc[2][ci] += p2.x * v0 + p2.y * v1;
                    acc[3][ci] += p3.x * v0 + p3.y * v1;
                }
            }
        }
    }

    // ---- epilogue: normalize, transpose through LDS, coalesced store ----
    __syncthreads();
    float* ot = smem + 2304;           // 256*33 = 8448 floats, reuses v+p region
    {
        float linv0 = 1.0f / l_s[ib + 0];
        float linv1 = 1.0f / l_s[ib + 1];
        float linv2 = 1.0f / l_s[ib + 2];
        float linv3 = 1.0f / l_s[ib + 3];
        #pragma unroll
        for (int ci = 0; ci < 8; ++ci) {
            int c = cg + 32 * ci;
            ot[c * OTS + ib + 0] = acc[0][ci] * linv0;
            ot[c * OTS + ib + 1] = acc[1][ci] * linv1;
            ot[c * OTS + ib + 2] = acc[2][ci] * linv2;
            ot[c * OTS + ib + 3] = acc[3][ci] * linv3;
        }
    }
    __syncthreads();
    {
        const float g = gamma[0];
        const int i = t & 31;
        const int c0 = t >> 5;         // 0..7
        for (int it = 0; it < 32; ++it) {
            int c = c0 + it * 8;
            float val = ot[c * OTS + i];
            size_t gi = ((size_t)b * CC + c) * NPIX + i0 + i;
            out[gi] = g * val + x[gi];
        }
    }
}

// ---------------------------------------------------------------------------
extern "C" void kernel_launch(void* const* d_in, const int* in_sizes, int n_in,
                              void* d_out, int out_size, void* d_ws, size_t ws_size,
                              hipStream_t stream) {
    const float* x     = (const float*)d_in[0];
    const float* mask  = (const float*)d_in[1];
    const float* Wq    = (const float*)d_in[2];
    const float* bq    = (const float*)d_in[3];
    const float* Wk    = (const float*)d_in[4];
    const float* bk    = (const float*)d_in[5];
    const float* Wv    = (const float*)d_in[6];
    const float* bv    = (const float*)d_in[7];
    const float* gamma = (const float*)d_in[8];
    float* out = (float*)d_out;

    float* ws = (float*)d_ws;
    float* q = ws;                                     // 4*32*4096
    float* k = q + (size_t)BATCH * CQN * NPIX;         // 4*32*4096
    float* v = k + (size_t)BATCH * CQN * NPIX;         // 4*256*4096

    proj_kernel<<<BATCH * (NPIX / 64), 256, 0, stream>>>(
        x, mask, Wq, bq, Wk, bk, Wv, bv, q, k, v);
    attn_kernel<<<BATCH * (NPIX / TI), 256, 0, stream>>>(
        q, k, v, x, gamma, out);
}

// Round 2
// 260.814 us; speedup vs baseline: 4.1860x; 4.1860x over previous
//
#include <hip/hip_runtime.h>
#include <math.h>

#define CC 256
#define CQN 32
#define NPIX 4096
#define BATCH 4

typedef __attribute__((ext_vector_type(8)))  short short8;
typedef __attribute__((ext_vector_type(4)))  short short4v;
typedef __attribute__((ext_vector_type(16))) float f32x16;

union FragU { short8 v; short s[8]; unsigned u[4]; short4v h2[2]; };

__device__ inline unsigned pkbf(float a, float b) {   // pack 2 floats -> 2 bf16 (RNE)
    unsigned x = __float_as_uint(a), y = __float_as_uint(b);
    x = (x + 0x7FFFu + ((x >> 16) & 1u)) >> 16;
    y = (y + 0x7FFFu + ((y >> 16) & 1u)) & 0xFFFF0000u;
    return x | y;
}
__device__ inline unsigned short bf1(float a) {
    unsigned x = __float_as_uint(a);
    return (unsigned short)((x + 0x7FFFu + ((x >> 16) & 1u)) >> 16);
}
__device__ inline f32x16 zero16() {
    f32x16 v;
    #pragma unroll
    for (int i = 0; i < 16; ++i) v[i] = 0.0f;
    return v;
}
__device__ inline f32x16 mfma32(short8 a, short8 b, f32x16 c) {
    return __builtin_amdgcn_mfma_f32_32x32x16_bf16(a, b, c, 0, 0, 0);
}

// ---------------------------------------------------------------------------
// proj: MFMA GEMM.  v-mode blocks (0..255): D[m=oc][n=p] -> v [C][N] bf16.
// qk-mode blocks (256..383): D[m=p][n=oc] -> qT,kT [N][32] bf16 (transposed).
// x tile staged to LDS as bf16 xs[c][p] (stride 132, 2-way conflicts only).
// ---------------------------------------------------------------------------
__global__ __launch_bounds__(256, 2) void proj_mfma(
    const float* __restrict__ x, const float* __restrict__ mask,
    const float* __restrict__ Wq, const float* __restrict__ bq,
    const float* __restrict__ Wk, const float* __restrict__ bk,
    const float* __restrict__ Wv, const float* __restrict__ bv,
    unsigned short* __restrict__ qT, unsigned short* __restrict__ kT,
    unsigned short* __restrict__ vws)
{
    __shared__ unsigned short xs[256 * 132];
    __shared__ float msh[128];
    __shared__ float bvs[128];

    const int t = threadIdx.x;
    const int bid = blockIdx.x;
    const int w = t >> 6, l = t & 63, L = l & 31, h = l >> 5;

    int b, p0, oc0; const bool vmode = bid < 256;
    if (vmode) { b = bid >> 6; int r6 = bid & 63; oc0 = (r6 >> 5) * 128; p0 = (r6 & 31) * 128; }
    else       { int id = bid - 256; b = id >> 5; p0 = (id & 31) * 128; oc0 = 0; }

    const float* xg = x + (size_t)b * CC * NPIX + p0;
    // stage x tile [256 c][128 p] as bf16
    for (int it2 = 0; it2 < 32; ++it2) {
        int c = (t >> 5) + 8 * it2;
        int pp = (t & 31) * 4;
        float4 xv = *(const float4*)(xg + (size_t)c * NPIX + pp);
        *(unsigned*)&xs[c * 132 + pp]     = pkbf(xv.x, xv.y);
        *(unsigned*)&xs[c * 132 + pp + 2] = pkbf(xv.z, xv.w);
    }
    if (vmode) { if (t < 128) bvs[t] = bv[oc0 + t]; }
    else       { if (t < 128) msh[t] = mask[(size_t)b * NPIX + p0 + t]; }
    __syncthreads();

    if (vmode) {
        const int ocw = oc0 + 32 * w;
        f32x16 acc[4];
        #pragma unroll
        for (int nt = 0; nt < 4; ++nt) acc[nt] = zero16();

        for (int s = 0; s < 16; ++s) {
            const int cb = 16 * s + 8 * h;
            const float* wr = Wv + (size_t)(ocw + L) * CC + cb;
            float4 wa = *(const float4*)(wr);
            float4 wb2 = *(const float4*)(wr + 4);
            FragU af;
            af.u[0] = pkbf(wa.x, wa.y);  af.u[1] = pkbf(wa.z, wa.w);
            af.u[2] = pkbf(wb2.x, wb2.y); af.u[3] = pkbf(wb2.z, wb2.w);
            #pragma unroll
            for (int nt = 0; nt < 4; ++nt) {
                FragU bf;
                #pragma unroll
                for (int r = 0; r < 8; ++r) bf.s[r] = (short)xs[(cb + r) * 132 + 32 * nt + L];
                acc[nt] = mfma32(af.v, bf.v, acc[nt]);
            }
        }
        unsigned short* vb = vws + (size_t)b * CC * NPIX + p0;
        #pragma unroll
        for (int nt = 0; nt < 4; ++nt)
            #pragma unroll
            for (int r = 0; r < 16; ++r) {
                int row = (r & 3) + 8 * (r >> 2) + 4 * h;
                float val = acc[nt][r] + bvs[32 * w + row];
                vb[(size_t)(ocw + row) * NPIX + 32 * nt + L] = bf1(val);
            }
    } else {
        f32x16 accq = zero16(), acck = zero16();
        for (int s = 0; s < 16; ++s) {
            const int cb = 16 * s + 8 * h;
            FragU af;
            #pragma unroll
            for (int r = 0; r < 8; ++r) af.s[r] = (short)xs[(cb + r) * 132 + 32 * w + L];
            const float* wqr = Wq + (size_t)L * CC + cb;
            float4 a0 = *(const float4*)(wqr), a1 = *(const float4*)(wqr + 4);
            FragU bfq;
            bfq.u[0] = pkbf(a0.x, a0.y); bfq.u[1] = pkbf(a0.z, a0.w);
            bfq.u[2] = pkbf(a1.x, a1.y); bfq.u[3] = pkbf(a1.z, a1.w);
            accq = mfma32(af.v, bfq.v, accq);
            const float* wkr = Wk + (size_t)L * CC + cb;
            float4 c0v = *(const float4*)(wkr), c1v = *(const float4*)(wkr + 4);
            FragU bfk;
            bfk.u[0] = pkbf(c0v.x, c0v.y); bfk.u[1] = pkbf(c0v.z, c0v.w);
            bfk.u[2] = pkbf(c1v.x, c1v.y); bfk.u[3] = pkbf(c1v.z, c1v.w);
            acck = mfma32(af.v, bfk.v, acck);
        }
        const float biasq = bq[L], biask = bk[L];
        unsigned short* qb2 = qT + ((size_t)b * NPIX + p0) * 32;
        unsigned short* kb2 = kT + ((size_t)b * NPIX + p0) * 32;
        #pragma unroll
        for (int r = 0; r < 16; ++r) {
            int prow = 32 * w + (r & 3) + 8 * (r >> 2) + 4 * h;
            float mv = msh[prow];
            qb2[(size_t)prow * 32 + L] = bf1((accq[r] + biasq) * mv);
            kb2[(size_t)prow * 32 + L] = bf1((acck[r] + biask) * mv);
        }
    }
}

// ---------------------------------------------------------------------------
// attn: flash, Mtile=32 queries/block, Jtile=128/iter (32 j per wave for S^T),
// PV: each wave owns 64 channels of O^T.  XCD-pinned by batch.
// ---------------------------------------------------------------------------
__global__ __launch_bounds__(256, 2) void attn_mfma(
    const unsigned short* __restrict__ qT, const unsigned short* __restrict__ kT,
    const unsigned short* __restrict__ vws, const float* __restrict__ x,
    const float* __restrict__ gamma, float* __restrict__ out)
{
    __shared__ unsigned short p_lds[32 * 132];
    __shared__ float red[2][128];

    const int t = threadIdx.x;
    const int bid = blockIdx.x;
    const int b  = (bid >> 1) & 3;                    // XCD-pinned: batch = xcd/2
    const int it = (bid >> 3) * 2 + (bid & 1);
    const int i0 = it * 32;
    const int w = t >> 6, l = t & 63, L = l & 31, h = l >> 5;

    const unsigned short* qrow = qT + ((size_t)b * NPIX + i0 + L) * 32 + 8 * h;
    short8 qf0 = *(const short8*)(qrow);
    short8 qf1 = *(const short8*)(qrow + 16);

    const unsigned short* kbase = kT + (size_t)b * NPIX * 32;
    const unsigned short* vrow0 = vws + ((size_t)b * CC + 64 * w + L) * NPIX;
    const unsigned short* vrow1 = vrow0 + (size_t)32 * NPIX;

    f32x16 acc0 = zero16(), acc1 = zero16();
    float m_run = -INFINITY, l_run = 0.0f;

    for (int jt = 0; jt < NPIX / 128; ++jt) {
        const int j0 = jt * 128;
        const int jw = j0 + 32 * w;

        // ---- S^T = K * Q  (m=j, n=i, k=c) ----
        const unsigned short* krow = kbase + (size_t)(jw + L) * 32 + 8 * h;
        short8 kf0 = *(const short8*)(krow);
        short8 kf1 = *(const short8*)(krow + 16);
        f32x16 s_acc = zero16();
        s_acc = mfma32(kf0, qf0, s_acc);
        s_acc = mfma32(kf1, qf1, s_acc);

        // ---- per-i max over this wave's 32 j ----
        float mx = s_acc[0];
        #pragma unroll
        for (int r = 1; r < 16; ++r) mx = fmaxf(mx, s_acc[r]);
        mx = fmaxf(mx, __shfl_xor(mx, 32));
        if (l < 32) red[0][w * 32 + l] = mx;
        __syncthreads();

        float tmax = fmaxf(fmaxf(red[0][L], red[0][32 + L]),
                           fmaxf(red[0][64 + L], red[0][96 + L]));
        float m_new = fmaxf(m_run, tmax);
        float alpha = __expf(m_run - m_new);
        m_run = m_new;

        // ---- exp, partial sum, pack P into LDS ----
        float pv[16]; float ssum = 0.0f;
        #pragma unroll
        for (int r = 0; r < 16; ++r) { pv[r] = __expf(s_acc[r] - m_new); ssum += pv[r]; }
        ssum += __shfl_xor(ssum, 32);
        if (l < 32) red[1][w * 32 + l] = ssum;
        #pragma unroll
        for (int g = 0; g < 4; ++g) {
            unsigned lo = pkbf(pv[4 * g + 0], pv[4 * g + 1]);
            unsigned hi = pkbf(pv[4 * g + 2], pv[4 * g + 3]);
            int col = 32 * w + 8 * g + 4 * h;
            *(uint2*)&p_lds[L * 132 + col] = make_uint2(lo, hi);
        }
        __syncthreads();

        float tsum = (red[1][L] + red[1][32 + L]) + (red[1][64 + L] + red[1][96 + L]);
        l_run = l_run * alpha + tsum;

        // ---- rescale O^T, then O^T += V * P^T ----
        #pragma unroll
        for (int r = 0; r < 16; ++r) { acc0[r] *= alpha; acc1[r] *= alpha; }

        const unsigned short* prow = p_lds + L * 132;
        #pragma unroll
        for (int s = 0; s < 8; ++s) {
            const int off = 16 * s + 8 * h;
            FragU pf;
            pf.h2[0] = *(const short4v*)(prow + off);
            pf.h2[1] = *(const short4v*)(prow + off + 4);
            short8 vf0 = *(const short8*)(vrow0 + j0 + off);
            short8 vf1 = *(const short8*)(vrow1 + j0 + off);
            acc0 = mfma32(vf0, pf.v, acc0);
            acc1 = mfma32(vf1, pf.v, acc1);
        }
    }

    // ---- epilogue: out = gamma * O/l + x ----
    const float linv = 1.0f / l_run;
    const float g = gamma[0] * linv;
    #pragma unroll
    for (int r = 0; r < 16; ++r) {
        int row = (r & 3) + 8 * (r >> 2) + 4 * h;
        size_t i_a = ((size_t)b * CC + 64 * w + row) * NPIX + i0 + L;
        size_t i_b = i_a + (size_t)32 * NPIX;
        out[i_a] = g * acc0[r] + x[i_a];
        out[i_b] = g * acc1[r] + x[i_b];
    }
}

// ---------------------------------------------------------------------------
extern "C" void kernel_launch(void* const* d_in, const int* in_sizes, int n_in,
                              void* d_out, int out_size, void* d_ws, size_t ws_size,
                              hipStream_t stream) {
    const float* x     = (const float*)d_in[0];
    const float* mask  = (const float*)d_in[1];
    const float* Wq    = (const float*)d_in[2];
    const float* bq    = (const float*)d_in[3];
    const float* Wk    = (const float*)d_in[4];
    const float* bk    = (const float*)d_in[5];
    const float* Wv    = (const float*)d_in[6];
    const float* bv    = (const float*)d_in[7];
    const float* gamma = (const float*)d_in[8];
    float* out = (float*)d_out;

    unsigned short* ws = (unsigned short*)d_ws;
    unsigned short* qT  = ws;                                   // [B][N][32]
    unsigned short* kT  = qT + (size_t)BATCH * NPIX * 32;       // [B][N][32]
    unsigned short* vws = kT + (size_t)BATCH * NPIX * 32;       // [B][C][N]

    proj_mfma<<<384, 256, 0, stream>>>(x, mask, Wq, bq, Wk, bk, Wv, bv, qT, kT, vws);
    attn_mfma<<<512, 256, 0, stream>>>(qT, kT, vws, x, gamma, out);
}

// Round 3
// 191.025 us; speedup vs baseline: 5.7153x; 1.3653x over previous
//
#include <hip/hip_runtime.h>
#include <math.h>

#define CC 256
#define NPIX 4096
#define BATCH 4

typedef __attribute__((ext_vector_type(8)))  short short8;
typedef __attribute__((ext_vector_type(16))) float f32x16;

union FragU { short8 v; short s[8]; unsigned u[4]; };

__device__ inline unsigned pkbf(float a, float b) {   // pack 2 floats -> 2 bf16 (RNE)
    unsigned x = __float_as_uint(a), y = __float_as_uint(b);
    x = (x + 0x7FFFu + ((x >> 16) & 1u)) >> 16;
    y = (y + 0x7FFFu + ((y >> 16) & 1u)) & 0xFFFF0000u;
    return x | y;
}
__device__ inline unsigned short bf1(float a) {
    unsigned x = __float_as_uint(a);
    return (unsigned short)((x + 0x7FFFu + ((x >> 16) & 1u)) >> 16);
}
__device__ inline f32x16 zero16() {
    f32x16 v;
    #pragma unroll
    for (int i = 0; i < 16; ++i) v[i] = 0.0f;
    return v;
}
__device__ inline f32x16 mfma32(short8 a, short8 b, f32x16 c) {
    return __builtin_amdgcn_mfma_f32_32x32x16_bf16(a, b, c, 0, 0, 0);
}

// ---------------------------------------------------------------------------
// proj: no LDS, no barriers. Wave = (32 W-rows, 128 pixels).
// D[m=p][n=oc]. A = x^T fragments via 8 coalesced dword loads + packs.
// B = W rows preloaded to 64 VGPRs (reused across 4 n-tiles).
// Outputs: qT/kT [N][32] bf16;  v in interleaved vI[b][cg][jo=j/8][c&31][8j].
// ---------------------------------------------------------------------------
__global__ __launch_bounds__(256, 2) void proj_mfma(
    const float* __restrict__ x, const float* __restrict__ mask,
    const float* __restrict__ Wq, const float* __restrict__ bq,
    const float* __restrict__ Wk, const float* __restrict__ bk,
    const float* __restrict__ Wv, const float* __restrict__ bv,
    unsigned short* __restrict__ qT, unsigned short* __restrict__ kT,
    unsigned short* __restrict__ vI)
{
    const int t = threadIdx.x;
    const int w = t >> 6, L = t & 31, h = (t >> 5) & 1;
    const int gid = blockIdx.x * 4 + w;
    const int b   = gid / 320;
    const int rem = gid % 320;
    const int pt  = rem / 10;          // 32 p-tiles of 128
    const int ocg = rem % 10;          // 0=q, 1=k, 2..9=v c-groups
    const int p0  = pt * 128;

    const float* Wrow; const float* bias; int oc0;
    if (ocg == 0)      { Wrow = Wq; bias = bq; oc0 = 0; }
    else if (ocg == 1) { Wrow = Wk; bias = bk; oc0 = 0; }
    else               { Wrow = Wv; bias = bv; oc0 = (ocg - 2) * 32; }

    // preload B frags: B[k=c][n=oc], lane n = L, k = 16s + 8h + 0..7
    FragU wf[16];
    const float* wr = Wrow + (size_t)(oc0 + L) * CC + 8 * h;
    #pragma unroll
    for (int s = 0; s < 16; ++s) {
        float4 a0 = *(const float4*)(wr + 16 * s);
        float4 a1 = *(const float4*)(wr + 16 * s + 4);
        wf[s].u[0] = pkbf(a0.x, a0.y); wf[s].u[1] = pkbf(a0.z, a0.w);
        wf[s].u[2] = pkbf(a1.x, a1.y); wf[s].u[3] = pkbf(a1.z, a1.w);
    }
    const float bcol = bias[oc0 + L];
    const float* xb = x + (size_t)b * CC * NPIX;
    const float* mb = mask + (size_t)b * NPIX;

    for (int nt = 0; nt < 4; ++nt) {
        const int pp = p0 + 32 * nt;
        f32x16 acc = zero16();
        #pragma unroll
        for (int s = 0; s < 16; ++s) {
            // A[m=p][k=c]: lane m = pp+L, k = 16s+8h+r -> 8 coalesced dword loads
            const float* xc = xb + (size_t)(16 * s + 8 * h) * NPIX + pp + L;
            float a0 = xc[0];
            float a1 = xc[NPIX];
            float a2 = xc[2 * NPIX];
            float a3 = xc[3 * NPIX];
            float a4 = xc[4 * NPIX];
            float a5 = xc[5 * NPIX];
            float a6 = xc[6 * NPIX];
            float a7 = xc[7 * NPIX];
            FragU af;
            af.u[0] = pkbf(a0, a1); af.u[1] = pkbf(a2, a3);
            af.u[2] = pkbf(a4, a5); af.u[3] = pkbf(a6, a7);
            acc = mfma32(af.v, wf[s].v, acc);
        }
        if (ocg < 2) {
            unsigned short* dst = (ocg ? kT : qT) + (size_t)b * NPIX * 32;
            #pragma unroll
            for (int r = 0; r < 16; ++r) {
                int prow = (r & 3) + 8 * (r >> 2) + 4 * h;
                float mv = mb[pp + prow];
                dst[(size_t)(pp + prow) * 32 + L] = bf1((acc[r] + bcol) * mv);
            }
        } else {
            const int cg = ocg - 2;
            unsigned short* vbp = vI + (size_t)(b * 8 + cg) * 512 * 32 * 8;
            #pragma unroll
            for (int m = 0; m < 4; ++m) {
                // rows r=4m+rr -> j = pp + 8m + 4h + rr: chunk jo = pp/8 + m, pos 4h+rr
                int jo = (pp >> 3) + m;
                unsigned lo = pkbf(acc[4 * m]     + bcol, acc[4 * m + 1] + bcol);
                unsigned hi = pkbf(acc[4 * m + 2] + bcol, acc[4 * m + 3] + bcol);
                *(uint2*)(vbp + ((size_t)jo * 32 + L) * 8 + 4 * h) = make_uint2(lo, hi);
            }
        }
    }
}

// ---------------------------------------------------------------------------
// attn: wave = (32-query tile, 1024-j quarter). Barrier-free K-loop:
// wave-local online softmax (i = lane&31), in-register P C/D->B transform via
// shfl_xor(32), O^T (256c x 32i) in 128 VGPRs. 4-wave merge at end via LDS.
// ---------------------------------------------------------------------------
__global__ __launch_bounds__(256, 2) void attn_mfma(
    const unsigned short* __restrict__ qT, const unsigned short* __restrict__ kT,
    const unsigned short* __restrict__ vI, const float* __restrict__ x,
    const float* __restrict__ gamma, float* __restrict__ out)
{
    __shared__ float mls[2][4][32];
    __shared__ float obuf[4][2048];

    const int t = threadIdx.x;
    const int w = t >> 6, l = t & 63, L = l & 31, h = l >> 5;
    const int bid = blockIdx.x;
    const int b  = (bid >> 1) & 3;                 // XCD-pinned by batch
    const int it = (bid >> 3) * 2 + (bid & 1);
    const int i0 = it * 32;

    const unsigned short* qrow = qT + ((size_t)b * NPIX + i0 + L) * 32 + 8 * h;
    short8 qf0 = *(const short8*)(qrow);
    short8 qf1 = *(const short8*)(qrow + 16);

    const unsigned short* kb = kT + (size_t)b * NPIX * 32;
    const unsigned short* vb = vI + (size_t)b * 8 * 512 * 32 * 8;

    f32x16 acc[8];
    #pragma unroll
    for (int cg = 0; cg < 8; ++cg) acc[cg] = zero16();
    float m_run = -INFINITY, l_run = 0.0f;

    const int jbase = w * 1024;
    const unsigned short* kr0 = kb + (size_t)(jbase + L) * 32 + 8 * h;
    short8 ka0 = *(const short8*)(kr0);
    short8 ka1 = *(const short8*)(kr0 + 16);
    short8 kb0 = *(const short8*)(kr0 + 1024);
    short8 kb1 = *(const short8*)(kr0 + 1024 + 16);

    for (int itr = 0; itr < 16; ++itr) {
        const int j0 = jbase + itr * 64;

        f32x16 s0 = zero16(), s1 = zero16();
        s0 = mfma32(ka0, qf0, s0);
        s0 = mfma32(ka1, qf1, s0);
        s1 = mfma32(kb0, qf0, s1);
        s1 = mfma32(kb1, qf1, s1);

        if (itr < 15) {        // prefetch next K tile
            const unsigned short* kr = kb + (size_t)(j0 + 64 + L) * 32 + 8 * h;
            ka0 = *(const short8*)(kr);
            ka1 = *(const short8*)(kr + 16);
            kb0 = *(const short8*)(kr + 1024);
            kb1 = *(const short8*)(kr + 1024 + 16);
        }
        // prefetch V step 0
        short8 vpre[8];
        {
            const size_t jox = (size_t)(j0 >> 3) + h;
            #pragma unroll
            for (int cg = 0; cg < 8; ++cg)
                vpre[cg] = *(const short8*)(vb + (((size_t)cg * 512 + jox) * 32 + L) * 8);
        }

        // ---- wave-local online softmax (i = L, j spans regs + lane^32) ----
        float tmax = s0[0];
        #pragma unroll
        for (int r = 1; r < 16; ++r) tmax = fmaxf(tmax, s0[r]);
        #pragma unroll
        for (int r = 0; r < 16; ++r) tmax = fmaxf(tmax, s1[r]);
        tmax = fmaxf(tmax, __shfl_xor(tmax, 32));
        float m_new = fmaxf(m_run, tmax);
        if (__ballot(tmax > m_run)) {
            float alpha = __expf(m_run - m_new);
            l_run *= alpha;
            #pragma unroll
            for (int cg = 0; cg < 8; ++cg)
                #pragma unroll
                for (int r = 0; r < 16; ++r) acc[cg][r] *= alpha;
        }
        m_run = m_new;

        float ssum = 0.0f;
        #pragma unroll
        for (int r = 0; r < 16; ++r) { s0[r] = __expf(s0[r] - m_new); ssum += s0[r]; }
        #pragma unroll
        for (int r = 0; r < 16; ++r) { s1[r] = __expf(s1[r] - m_new); ssum += s1[r]; }
        ssum += __shfl_xor(ssum, 32);
        l_run += ssum;

        // ---- pack P (C/D layout) and exchange -> B-operand frags ----
        unsigned ua[8], ub[8], pa[8], pb[8];
        #pragma unroll
        for (int m = 0; m < 4; ++m) {
            ua[2 * m]     = pkbf(s0[4 * m],     s0[4 * m + 1]);
            ua[2 * m + 1] = pkbf(s0[4 * m + 2], s0[4 * m + 3]);
            ub[2 * m]     = pkbf(s1[4 * m],     s1[4 * m + 1]);
            ub[2 * m + 1] = pkbf(s1[4 * m + 2], s1[4 * m + 3]);
        }
        #pragma unroll
        for (int q = 0; q < 8; ++q) {
            pa[q] = (unsigned)__shfl_xor((int)ua[q], 32);
            pb[q] = (unsigned)__shfl_xor((int)ub[q], 32);
        }
        FragU pf[4];
        #pragma unroll
        for (int s = 0; s < 2; ++s) {
            pf[s].u[0] = h ? pa[4 * s + 2] : ua[4 * s];
            pf[s].u[1] = h ? pa[4 * s + 3] : ua[4 * s + 1];
            pf[s].u[2] = h ? ua[4 * s + 2] : pa[4 * s];
            pf[s].u[3] = h ? ua[4 * s + 3] : pa[4 * s + 1];
            pf[s + 2].u[0] = h ? pb[4 * s + 2] : ub[4 * s];
            pf[s + 2].u[1] = h ? pb[4 * s + 3] : ub[4 * s + 1];
            pf[s + 2].u[2] = h ? ub[4 * s + 2] : pb[4 * s];
            pf[s + 2].u[3] = h ? ub[4 * s + 3] : pb[4 * s + 1];
        }

        // ---- O^T += V * P^T : 4 K-steps x 8 c-groups ----
        #pragma unroll
        for (int s = 0; s < 4; ++s) {
            short8 vcur[8];
            #pragma unroll
            for (int cg = 0; cg < 8; ++cg) vcur[cg] = vpre[cg];
            if (s < 3) {
                const size_t jox = (size_t)((j0 + 16 * (s + 1)) >> 3) + h;
                #pragma unroll
                for (int cg = 0; cg < 8; ++cg)
                    vpre[cg] = *(const short8*)(vb + (((size_t)cg * 512 + jox) * 32 + L) * 8);
            }
            #pragma unroll
            for (int cg = 0; cg < 8; ++cg)
                acc[cg] = mfma32(vcur[cg], pf[s].v, acc[cg]);
        }
    }

    // ---- merge 4 j-quarter waves ----
    if (h == 0) { mls[0][w][L] = m_run; mls[1][w][L] = l_run; }
    __syncthreads();
    float m0 = mls[0][0][L], m1 = mls[0][1][L], m2 = mls[0][2][L], m3 = mls[0][3][L];
    float ms = fmaxf(fmaxf(m0, m1), fmaxf(m2, m3));
    float f0 = __expf(m0 - ms), f1 = __expf(m1 - ms);
    float f2 = __expf(m2 - ms), f3 = __expf(m3 - ms);
    float lstar = f0 * mls[1][0][L] + f1 * mls[1][1][L]
                + f2 * mls[1][2][L] + f3 * mls[1][3][L];
    float fw = (w == 0) ? f0 : (w == 1) ? f1 : (w == 2) ? f2 : f3;
    const float scale = gamma[0] / lstar;

    #pragma unroll
    for (int cg = 0; cg < 8; ++cg)
        #pragma unroll
        for (int r = 0; r < 16; ++r) acc[cg][r] *= fw;

    const int ti = t & 31, trow = t >> 5;
    for (int ck = 0; ck < 4; ++ck) {
        #pragma unroll
        for (int half = 0; half < 2; ++half) {
            #pragma unroll
            for (int r = 0; r < 16; ++r) {
                int prow = (r & 3) + 8 * (r >> 2) + 4 * h;
                obuf[w][half * 1024 + prow * 32 + L] = acc[2 * ck + half][r];
            }
        }
        __syncthreads();
        #pragma unroll
        for (int rr = 0; rr < 8; ++rr) {
            int cr = trow + 8 * rr;
            int idx = cr * 32 + ti;
            float sum = obuf[0][idx] + obuf[1][idx] + obuf[2][idx] + obuf[3][idx];
            size_t gi = ((size_t)b * CC + ck * 64 + cr) * NPIX + i0 + ti;
            out[gi] = scale * sum + x[gi];
        }
        __syncthreads();
    }
}

// ---------------------------------------------------------------------------
extern "C" void kernel_launch(void* const* d_in, const int* in_sizes, int n_in,
                              void* d_out, int out_size, void* d_ws, size_t ws_size,
                              hipStream_t stream) {
    const float* x     = (const float*)d_in[0];
    const float* mask  = (const float*)d_in[1];
    const float* Wq    = (const float*)d_in[2];
    const float* bq    = (const float*)d_in[3];
    const float* Wk    = (const float*)d_in[4];
    const float* bk    = (const float*)d_in[5];
    const float* Wv    = (const float*)d_in[6];
    const float* bv    = (const float*)d_in[7];
    const float* gamma = (const float*)d_in[8];
    float* out = (float*)d_out;

    unsigned short* ws = (unsigned short*)d_ws;
    unsigned short* qT = ws;                                  // [B][N][32]
    unsigned short* kT = qT + (size_t)BATCH * NPIX * 32;      // [B][N][32]
    unsigned short* vI = kT + (size_t)BATCH * NPIX * 32;      // [B][8][512][32][8]

    proj_mfma<<<320, 256, 0, stream>>>(x, mask, Wq, bq, Wk, bk, Wv, bv, qT, kT, vI);
    attn_mfma<<<512, 256, 0, stream>>>(qT, kT, vI, x, gamma, out);
}